// Round 9
// baseline (1055.750 us; speedup 1.0000x reference)
//
#include <hip/hip_runtime.h>
#include <stdint.h>

// Instant-NGP hash-grid + MLP.
// encode: level-major XCD-owned; corner-PAIR gathers (request-count-bound,
//   ~1.7 cyc/lane-request — near TA floor).
// prep: W1/W2 -> bf16 swizzled fragment image in d_ws (once per launch).
// mlp: persistent blocks; ALL W fragments hoisted to VGPRs once per block;
//   layer1 computed operand-swapped (D = h1^T) so h1 stores are 2x b64/lane;
//   2 barriers/group; X prefetched one group ahead into registers.

#define NLV 32
#define LOG2T 19
#define TSZ (1u << LOG2T)
#define TMASK (TSZ - 1u)
#define PRIME2 2654435761u
#define PRIME3 805459861u

typedef float v2f __attribute__((ext_vector_type(2)));
typedef float f32x4 __attribute__((ext_vector_type(4)));
typedef float f32x4u __attribute__((ext_vector_type(4), aligned(8)));
typedef short bf16x8 __attribute__((ext_vector_type(8)));
typedef uint32_t u32x4 __attribute__((ext_vector_type(4)));
typedef uint32_t u32x2 __attribute__((ext_vector_type(2)));

__device__ __forceinline__ uint32_t pack_bf16(float a, float b) {
  uint32_t ua = __float_as_uint(a), ub = __float_as_uint(b);
  ua = (ua + 0x7fffu + ((ua >> 16) & 1u)) >> 16;
  ub = (ub + 0x7fffu + ((ub >> 16) & 1u)) >> 16;
  return ua | (ub << 16);
}
__device__ __forceinline__ uint16_t bf16_rne(float a) {
  uint32_t u = __float_as_uint(a);
  u = (u + 0x7fffu + ((u >> 16) & 1u)) >> 16;
  return (uint16_t)u;
}

__global__ __launch_bounds__(256) void encode_kernel(
    const float* __restrict__ x, const float* __restrict__ emb,
    uint32_t* __restrict__ feats, int offset, int count, int chunkCap, int bpl)
{
  const int bid = (int)blockIdx.x;
  const int xcd = bid & 7;
  const int j = bid >> 3;
  const int phase = j / bpl;
  const int within = j - phase * bpl;
  const int l = xcd + (phase << 3);

  const float scale = (float)((double)(1ULL << l) - 1.0);
  const uint32_t r = 1u << l, rr = r * r;
  const bool dense = (l <= 6);
  const v2f* __restrict__ embl = (const v2f*)(emb + ((size_t)l << (LOG2T + 1)));

  #pragma unroll
  for (int k = 0; k < 4; ++k) {
    int li = within * 1024 + k * 256 + (int)threadIdx.x;
    if (li < count) {
      int p = offset + li;
      float xv = __builtin_nontemporal_load(&x[3 * p + 0]);
      float yv = __builtin_nontemporal_load(&x[3 * p + 1]);
      float zv = __builtin_nontemporal_load(&x[3 * p + 2]);
      // EXACT replication of reference rounding: mul RN then add RN (no FMA!)
      float px = __fadd_rn(__fmul_rn(xv, scale), 0.5f);
      float py = __fadd_rn(__fmul_rn(yv, scale), 0.5f);
      float pz = __fadd_rn(__fmul_rn(zv, scale), 0.5f);
      float bx = floorf(px), by = floorf(py), bz = floorf(pz);
      float fx = __fsub_rn(px, bx), fy = __fsub_rn(py, by), fz = __fsub_rn(pz, bz);
      uint32_t gx = (uint32_t)bx, gy = (uint32_t)by, gz = (uint32_t)bz;
      float wx0 = __fsub_rn(1.0f, fx), wx1 = fx;
      float wy0 = __fsub_rn(1.0f, fy), wy1 = fy;
      float wz0 = __fsub_rn(1.0f, fz), wz1 = fz;

      float f0 = 0.0f, f1 = 0.0f;
      // 4 (y,z) corner pairs; x-corners merged into one 16B load when adjacent.
      #pragma unroll
      for (int cp = 0; cp < 4; ++cp) {
        uint32_t cy = gy + (uint32_t)(cp & 1);
        uint32_t cz = gz + (uint32_t)(cp >> 1);
        float wyz = __fmul_rn((cp & 1) ? wy1 : wy0, (cp >> 1) ? wz1 : wz0);
        v2f e0, e1;
        if (dense) {
          // idx1 = idx0 + 1: one (possibly 8B-aligned) 16B load
          uint32_t i0 = gx + cy * r + cz * rr;
          f32x4 e2 = *(const f32x4u*)&embl[i0];
          e0[0] = e2.x; e0[1] = e2.y; e1[0] = e2.z; e1[1] = e2.w;
        } else {
          uint32_t h = (cy * PRIME2) ^ (cz * PRIME3);
          uint32_t i0 = (gx ^ h) & TMASK;
          if (!(gx & 1u)) {
            // idx1 = idx0 ^ 1: aligned pair {i0&~1, i0|1}
            f32x4 e2 = *(const f32x4*)&embl[i0 & ~1u];
            bool odd = (i0 & 1u) != 0u;
            e0[0] = odd ? e2.z : e2.x; e0[1] = odd ? e2.w : e2.y;
            e1[0] = odd ? e2.x : e2.z; e1[1] = odd ? e2.y : e2.w;
          } else {
            uint32_t i1 = ((gx + 1u) ^ h) & TMASK;
            e0 = embl[i0];
            e1 = embl[i1];
          }
        }
        float w0 = __fmul_rn(wx0, wyz), w1 = __fmul_rn(wx1, wyz);
        f0 = fmaf(w0, e0[0], f0); f1 = fmaf(w0, e0[1], f1);
        f0 = fmaf(w1, e1[0], f0); f1 = fmaf(w1, e1[1], f1);
      }
      __builtin_nontemporal_store(pack_bf16(f0, f1),
                                  &feats[(size_t)l * (size_t)chunkCap + li]);
    }
  }
}

// W1 -> wimg[0..16KB): [n][64k] bf16, byte addr n*128 + ((k*2)^((n&7)<<4))
// W2 -> wimg[16KB..48KB): [n][128k] bf16, byte addr 16384 + n*256 + ((k*2)^((n&7)<<4))
__global__ __launch_bounds__(512) void prep_kernel(
    const float* __restrict__ W1, const float* __restrict__ W2,
    uint16_t* __restrict__ wimg)
{
  int i = (int)blockIdx.x * 512 + (int)threadIdx.x;
  if (i < 8192) {
    int k = i >> 7, n = i & 127;
    wimg[(n * 128 + ((k * 2) ^ ((n & 7) << 4))) >> 1] = bf16_rne(W1[i]);
  } else if (i < 24576) {
    int t = i - 8192;
    int k = t >> 7, n = t & 127;
    wimg[(16384 + n * 256 + ((k * 2) ^ ((n & 7) << 4))) >> 1] = bf16_rne(W2[t]);
  }
}

#define MLP_G 64   // points per group

__global__ __launch_bounds__(256, 1) void mlp_kernel(
    const uint32_t* __restrict__ feats, const uint16_t* __restrict__ wimg,
    const float* __restrict__ b1, const float* __restrict__ b2,
    const float* __restrict__ W3, const float* __restrict__ b3,
    float* __restrict__ out, int offset, int count, int chunkCap, int nGroups)
{
  __shared__ char lds[24576];
  char* xb = lds;            // 64 pts x 128B : X bf16x64, swizzled rows
  char* hb = lds + 8192;     // 64 pts x 256B : h1 bf16x128, swizzled rows

  const int tid = (int)threadIdx.x;
  const int lane = tid & 63;
  const int w = tid >> 6;        // wave 0..3
  const int col = lane & 15;
  const int kh = lane >> 4;      // k-group 0..3
  const char* wbytes = (const char*)wimg;

  // ---- hoist ALL weight fragments into VGPRs (once per block) ----
  bf16x8 w1f[2][8], w2f[4][8];
  #pragma unroll
  for (int nt = 0; nt < 8; ++nt) {
    int n = nt * 16 + col;
    #pragma unroll
    for (int kt = 0; kt < 2; ++kt)
      w1f[kt][nt] = *(const bf16x8*)(wbytes + n * 128 +
                        ((kt * 64 + kh * 16) ^ ((n & 7) << 4)));
    #pragma unroll
    for (int q = 0; q < 4; ++q)
      w2f[q][nt] = *(const bf16x8*)(wbytes + 16384 + n * 256 +
                        ((q * 64 + kh * 16) ^ ((n & 7) << 4)));
  }
  float bias1r[8][4];            // b1 indexed by h1^T row n' = nt*16+kh*4+rg
  #pragma unroll
  for (int nt = 0; nt < 8; ++nt)
    #pragma unroll
    for (int rg = 0; rg < 4; ++rg)
      bias1r[nt][rg] = b1[nt * 16 + kh * 4 + rg];
  float bias2[8], w3v[8];
  #pragma unroll
  for (int nt = 0; nt < 8; ++nt) {
    bias2[nt] = b2[nt * 16 + col];
    w3v[nt] = W3[nt * 16 + col];
  }
  const float b3v = b3[0];

  const int pp = w * 16 + col;   // this wave's point row (0..63)
  const int sp = tid & 63;       // staging point
  const int sq = tid >> 6;       // staging quarter: planes sq*8 .. sq*8+7

  int g = (int)blockIdx.x;
  // prefetch group g's X into registers
  u32x4 xr0, xr1;
  {
    int src = g * MLP_G + sp; if (src >= count) src = 0;
    int pl = sq * 8;
    xr0.x = __builtin_nontemporal_load(&feats[(size_t)(pl + 0) * chunkCap + src]);
    xr0.y = __builtin_nontemporal_load(&feats[(size_t)(pl + 1) * chunkCap + src]);
    xr0.z = __builtin_nontemporal_load(&feats[(size_t)(pl + 2) * chunkCap + src]);
    xr0.w = __builtin_nontemporal_load(&feats[(size_t)(pl + 3) * chunkCap + src]);
    xr1.x = __builtin_nontemporal_load(&feats[(size_t)(pl + 4) * chunkCap + src]);
    xr1.y = __builtin_nontemporal_load(&feats[(size_t)(pl + 5) * chunkCap + src]);
    xr1.z = __builtin_nontemporal_load(&feats[(size_t)(pl + 6) * chunkCap + src]);
    xr1.w = __builtin_nontemporal_load(&feats[(size_t)(pl + 7) * chunkCap + src]);
  }

  for (; g < nGroups; g += (int)gridDim.x) {
    // ---- write staged X regs to LDS (safe: all waves past prev L2 reads) ----
    *(u32x4*)(xb + sp * 128 + ((sq * 32 +  0) ^ ((sp & 7) << 4))) = xr0;
    *(u32x4*)(xb + sp * 128 + ((sq * 32 + 16) ^ ((sp & 7) << 4))) = xr1;
    __syncthreads();

    // ---- prefetch next group's X (hidden under MFMA) ----
    {
      int gn = g + (int)gridDim.x; if (gn >= nGroups) gn = g;
      int src = gn * MLP_G + sp; if (src >= count) src = 0;
      int pl = sq * 8;
      xr0.x = __builtin_nontemporal_load(&feats[(size_t)(pl + 0) * chunkCap + src]);
      xr0.y = __builtin_nontemporal_load(&feats[(size_t)(pl + 1) * chunkCap + src]);
      xr0.z = __builtin_nontemporal_load(&feats[(size_t)(pl + 2) * chunkCap + src]);
      xr0.w = __builtin_nontemporal_load(&feats[(size_t)(pl + 3) * chunkCap + src]);
      xr1.x = __builtin_nontemporal_load(&feats[(size_t)(pl + 4) * chunkCap + src]);
      xr1.y = __builtin_nontemporal_load(&feats[(size_t)(pl + 5) * chunkCap + src]);
      xr1.z = __builtin_nontemporal_load(&feats[(size_t)(pl + 6) * chunkCap + src]);
      xr1.w = __builtin_nontemporal_load(&feats[(size_t)(pl + 7) * chunkCap + src]);
    }

    // ---- layer 1, operand-swapped: D = W1^T x X = h1^T ----
    bf16x8 xa[2];
    #pragma unroll
    for (int kt = 0; kt < 2; ++kt)
      xa[kt] = *(const bf16x8*)(xb + pp * 128 +
                   ((kt * 64 + kh * 16) ^ ((pp & 7) << 4)));
    f32x4 acc[8];
    #pragma unroll
    for (int nt = 0; nt < 8; ++nt) acc[nt] = {0.f, 0.f, 0.f, 0.f};
    #pragma unroll
    for (int kt = 0; kt < 2; ++kt)
      #pragma unroll
      for (int nt = 0; nt < 8; ++nt)
        acc[nt] = __builtin_amdgcn_mfma_f32_16x16x32_bf16(
                      w1f[kt][nt], xa[kt], acc[nt], 0, 0, 0);

    // h1^T: lane holds h1[pp][n'=nt*16+kh*4+rg] -> 4 consecutive n' => b64 store
    #pragma unroll
    for (int nt = 0; nt < 8; ++nt) {
      uint32_t lo = pack_bf16(fmaxf(acc[nt][0] + bias1r[nt][0], 0.0f),
                              fmaxf(acc[nt][1] + bias1r[nt][1], 0.0f));
      uint32_t hi = pack_bf16(fmaxf(acc[nt][2] + bias1r[nt][2], 0.0f),
                              fmaxf(acc[nt][3] + bias1r[nt][3], 0.0f));
      u32x2 v; v.x = lo; v.y = hi;
      *(u32x2*)(hb + pp * 256 + ((nt * 32 + kh * 8) ^ ((pp & 7) << 4))) = v;
    }
    __syncthreads();

    // ---- layer 2 (W2 from registers) ----
    f32x4 acc2[8];
    #pragma unroll
    for (int nt = 0; nt < 8; ++nt) acc2[nt] = {0.f, 0.f, 0.f, 0.f};
    #pragma unroll
    for (int q = 0; q < 4; ++q) {
      bf16x8 ha = *(const bf16x8*)(hb + pp * 256 +
                      ((q * 64 + kh * 16) ^ ((pp & 7) << 4)));
      #pragma unroll
      for (int nt = 0; nt < 8; ++nt)
        acc2[nt] = __builtin_amdgcn_mfma_f32_16x16x32_bf16(
                       ha, w2f[q][nt], acc2[nt], 0, 0, 0);
    }

    // ---- layer 3: out = relu(h2) @ W3 + b3 ----
    float osum[4] = {0.f, 0.f, 0.f, 0.f};
    #pragma unroll
    for (int nt = 0; nt < 8; ++nt) {
      #pragma unroll
      for (int rg = 0; rg < 4; ++rg)
        osum[rg] = fmaf(fmaxf(acc2[nt][rg] + bias2[nt], 0.0f), w3v[nt], osum[rg]);
    }
    #pragma unroll
    for (int rg = 0; rg < 4; ++rg) {
      osum[rg] += __shfl_xor(osum[rg], 1);
      osum[rg] += __shfl_xor(osum[rg], 2);
      osum[rg] += __shfl_xor(osum[rg], 4);
      osum[rg] += __shfl_xor(osum[rg], 8);
    }
    const int base = g * MLP_G;
    #pragma unroll
    for (int rg = 0; rg < 4; ++rg) {
      if (col == rg) {
        int pr = base + w * 16 + kh * 4 + rg;
        if (pr < count) out[offset + pr] = osum[rg] + b3v;
      }
    }
  }
}

extern "C" void kernel_launch(void* const* d_in, const int* in_sizes, int n_in,
                              void* d_out, int out_size, void* d_ws, size_t ws_size,
                              hipStream_t stream) {
  const float* x   = (const float*)d_in[0];
  const float* emb = (const float*)d_in[1];
  const float* W1  = (const float*)d_in[2];
  const float* b1  = (const float*)d_in[3];
  const float* W2  = (const float*)d_in[4];
  const float* b2  = (const float*)d_in[5];
  const float* W3  = (const float*)d_in[6];
  const float* b3  = (const float*)d_in[7];
  float* out = (float*)d_out;
  const int N = in_sizes[0] / 3;

  uint16_t* wimg = (uint16_t*)d_ws;                       // 48KB W image
  uint32_t* feats = (uint32_t*)((char*)d_ws + 49152);
  const size_t perPoint = (size_t)NLV * sizeof(uint32_t); // 128 B/point
  size_t avail = (ws_size > 49152) ? ws_size - 49152 : 0;
  size_t capz = avail / perPoint;
  if (capz > (size_t)N) capz = (size_t)N;
  int cap = (int)capz & ~1023;
  if (cap <= 0) cap = (N < 1024) ? N : 1024;

  prep_kernel<<<48, 512, 0, stream>>>(W1, W2, wimg);

  for (int off = 0; off < N; off += cap) {
    int cnt = (N - off < cap) ? (N - off) : cap;
    int bpl = (cnt + 1023) / 1024;          // blocks per level
    encode_kernel<<<32 * bpl, 256, 0, stream>>>(x, emb, feats, off, cnt, cap, bpl);
    int nGroups = (cnt + MLP_G - 1) / MLP_G;
    int nb = nGroups < 2048 ? nGroups : 2048;
    mlp_kernel<<<nb, 256, 0, stream>>>(
        feats, wimg, b1, b2, W3, b3, out, off, cnt, cap, nGroups);
  }
}